// Round 1
// baseline (359.948 us; speedup 1.0000x reference)
//
#include <hip/hip_runtime.h>
#include <math.h>

#define EPS_F 1.1754943508222875e-38f

typedef __attribute__((ext_vector_type(8))) _Float16 half8;
typedef __attribute__((ext_vector_type(4))) float f32x4;

__device__ __forceinline__ unsigned short f2h(float f) {
  _Float16 h = (_Float16)f;
  return __builtin_bit_cast(unsigned short, h);
}

// async global->LDS, 16B per lane; LDS dest is wave-uniform base + lane*16
__device__ __forceinline__ void gload16(const void* g, void* l) {
  __builtin_amdgcn_global_load_lds(
      (const __attribute__((address_space(1))) void*)g,
      (__attribute__((address_space(3))) void*)l, 16, 0, 0);
}

// ---------------- prep: x transpose + f16 convert ----------------
// x[(b*512+c)*256 + p] = in[(b*256+p)*512 + c]
__global__ __launch_bounds__(256) void k_prep_x(const float* __restrict__ in,
                                                unsigned short* __restrict__ x) {
  __shared__ float t[32][33];
  int c0 = blockIdx.x * 32, p0 = blockIdx.y * 32, b = blockIdx.z;
  int tx = threadIdx.x & 31, ty = threadIdx.x >> 5;
#pragma unroll
  for (int i = ty; i < 32; i += 8)
    t[i][tx] = in[(b * 256 + p0 + i) * 512 + c0 + tx];
  __syncthreads();
#pragma unroll
  for (int i = ty; i < 32; i += 8)
    x[(b * 512 + c0 + i) * 256 + p0 + tx] = f2h(t[tx][i]);
}

// ---------------- prep: Wdiff = Wq - Wk (f16), Wv (f16), Wo (f16),
//                  bdiff, rsig, plus L1 sums of Wk/Wv ----------------
__global__ __launch_bounds__(256) void k_prep_w(
    const float* __restrict__ Wq, const float* __restrict__ Wk,
    const float* __restrict__ Wv, const float* __restrict__ Wo,
    const float* __restrict__ bq, const float* __restrict__ bk,
    const float* __restrict__ sigma,
    unsigned short* __restrict__ wd, unsigned short* __restrict__ wvh,
    unsigned short* __restrict__ woh, float* __restrict__ bdiff,
    float* __restrict__ rsig, float* __restrict__ acc) {
  __shared__ float r1[4], r2[4];
  int gid = blockIdx.x * 256 + threadIdx.x;  // 0..1048575
  int i4 = gid * 4;
  int rm = i4 >> 8, p = i4 & 255, m = rm & 255;
  const float4 wk = *(const float4*)(Wk + i4);
  const float4 wv = *(const float4*)(Wv + i4);
  const float4 wq = *(const float4*)(Wq + m * 256 + p);
  ushort4 d;
  d.x = f2h(wq.x - wk.x); d.y = f2h(wq.y - wk.y);
  d.z = f2h(wq.z - wk.z); d.w = f2h(wq.w - wk.w);
  *(ushort4*)(wd + i4) = d;
  ushort4 vv;
  vv.x = f2h(wv.x); vv.y = f2h(wv.y); vv.z = f2h(wv.z); vv.w = f2h(wv.w);
  *(ushort4*)(wvh + i4) = vv;
  float ak = fabsf(wk.x) + fabsf(wk.y) + fabsf(wk.z) + fabsf(wk.w);
  float av = fabsf(wv.x) + fabsf(wv.y) + fabsf(wv.z) + fabsf(wv.w);
  if (gid < 16384) {
    bdiff[gid] = bq[gid & 255] - bk[gid];
    rsig[gid] = 1.0f / (sigma[gid] + EPS_F);
  }
  if (gid < 65536) woh[gid] = f2h(Wo[gid]);
  int lane = threadIdx.x & 63, w = threadIdx.x >> 6;
#pragma unroll
  for (int dlt = 1; dlt < 64; dlt <<= 1) {
    ak += __shfl_xor(ak, dlt);
    av += __shfl_xor(av, dlt);
  }
  if (lane == 0) { r1[w] = ak; r2[w] = av; }
  __syncthreads();
  if (threadIdx.x == 0) {
    atomicAdd(acc + 1, r1[0] + r1[1] + r1[2] + r1[3]);
    atomicAdd(acc + 2, r2[0] + r2[1] + r2[2] + r2[3]);
  }
}

// ---------------- loss: ||Wq@Wo - I||^2 partial ----------------
__global__ __launch_bounds__(256) void k_wqwo(const float* __restrict__ Wq,
                                              const float* __restrict__ Wo,
                                              float* __restrict__ acc) {
  __shared__ float wq[256];
  __shared__ float red[4];
  int i = blockIdx.x, j = threadIdx.x;
  wq[j] = Wq[i * 256 + j];
  __syncthreads();
  float s = 0.f;
#pragma unroll 8
  for (int p = 0; p < 256; ++p) s = fmaf(wq[p], Wo[p * 256 + j], s);
  float d = s - (i == j ? 1.0f : 0.0f);
  float x = d * d;
#pragma unroll
  for (int dd = 1; dd < 64; dd <<= 1) x += __shfl_xor(x, dd);
  if ((j & 63) == 0) red[j >> 6] = x;
  __syncthreads();
  if (j == 0) atomicAdd(acc + 0, red[0] + red[1] + red[2] + red[3]);
}

// ---------------- fire: S = x@Wdiff^T (MFMA), fire = exp(-0.5/M * sum(((S+bd)*rs)^2)) ----------------
// grid: (8 r-groups, 64 bc-tiles), block 256 (4 waves), tile 64bc x 256m per r
__global__ __launch_bounds__(256) void k_fire(
    const unsigned short* __restrict__ xh, const unsigned short* __restrict__ wd,
    const float* __restrict__ bdiff, const float* __restrict__ rsig,
    float* __restrict__ fire) {
  __shared__ unsigned short Al[64 * 256];  // 32KB, full-K A tile
  __shared__ unsigned short Bl[256 * 64];  // 32KB, per-K-step B tile
  __shared__ float red[4][64];
  const int w = threadIdx.x >> 6, lane = threadIdx.x & 63;
  const int cl = lane & 15, kg = lane >> 4;
  const int bc0 = blockIdx.y * 64;
  const int rg0 = blockIdx.x * 8;
  // stage full A once: 64x256 f16 = 32 slabs of 1KB
#pragma unroll
  for (int j = 0; j < 8; ++j) {
    int s = w * 8 + j;
    int c = s * 64 + lane;
    int row = c >> 5, ko = (c & 31) * 8;
    gload16(xh + (bc0 + row) * 256 + ko, Al + s * 512);
  }
  for (int rr = 0; rr < 8; ++rr) {
    const int r = rg0 + rr;
    const unsigned short* wb = wd + r * 65536;
    f32x4 acc[4][4];
#pragma unroll
    for (int i = 0; i < 4; ++i)
#pragma unroll
      for (int j = 0; j < 4; ++j) acc[i][j] = (f32x4){0.f, 0.f, 0.f, 0.f};
#pragma unroll
    for (int ks = 0; ks < 4; ++ks) {
#pragma unroll
      for (int j = 0; j < 8; ++j) {
        int s = w * 8 + j;
        int c = s * 64 + lane;
        int row = c >> 3, ko = (c & 7) * 8;
        gload16(wb + row * 256 + ks * 64 + ko, Bl + s * 512);
      }
      __syncthreads();
#pragma unroll
      for (int kk = 0; kk < 2; ++kk) {
        half8 a[4], b[4];
        int ka = ks * 64 + kk * 32 + kg * 8;
        int kb = kk * 32 + kg * 8;
#pragma unroll
        for (int i = 0; i < 4; ++i)
          a[i] = *(const half8*)(Al + (i * 16 + cl) * 256 + ka);
#pragma unroll
        for (int j = 0; j < 4; ++j)
          b[j] = *(const half8*)(Bl + (w * 64 + j * 16 + cl) * 64 + kb);
#pragma unroll
        for (int i = 0; i < 4; ++i)
#pragma unroll
          for (int j = 0; j < 4; ++j)
            acc[i][j] = __builtin_amdgcn_mfma_f32_16x16x32_f16(a[i], b[j], acc[i][j], 0, 0, 0);
      }
      __syncthreads();
    }
    // epilogue: rowsum of ((acc+bd)*rs)^2 over this wave's 64 cols
    float rowsum[4][4];
#pragma unroll
    for (int i = 0; i < 4; ++i)
#pragma unroll
      for (int q = 0; q < 4; ++q) rowsum[i][q] = 0.f;
#pragma unroll
    for (int j = 0; j < 4; ++j) {
      int mi = r * 256 + w * 64 + j * 16 + cl;
      float bd = bdiff[mi], rs = rsig[mi];
#pragma unroll
      for (int i = 0; i < 4; ++i)
#pragma unroll
        for (int q = 0; q < 4; ++q) {
          float t = (acc[i][j][q] + bd) * rs;
          rowsum[i][q] += t * t;
        }
    }
#pragma unroll
    for (int dlt = 1; dlt < 16; dlt <<= 1)
#pragma unroll
      for (int i = 0; i < 4; ++i)
#pragma unroll
        for (int q = 0; q < 4; ++q) rowsum[i][q] += __shfl_xor(rowsum[i][q], dlt);
    if (cl == 0) {
#pragma unroll
      for (int i = 0; i < 4; ++i)
#pragma unroll
        for (int q = 0; q < 4; ++q) red[w][i * 16 + kg * 4 + q] = rowsum[i][q];
    }
    __syncthreads();
    if (threadIdx.x < 64) {
      float s = red[0][threadIdx.x] + red[1][threadIdx.x] + red[2][threadIdx.x] + red[3][threadIdx.x];
      fire[(bc0 + threadIdx.x) * 64 + r] = expf(-0.001953125f * s) + EPS_F;
    }
    __syncthreads();
  }
}

// ---------------- mask: per-row top-p over 64 rules, one wave per row ----------------
__global__ __launch_bounds__(256) void k_mask(const float* __restrict__ fire,
                                              float* __restrict__ nfs, float tau) {
  int w = threadIdx.x >> 6, lane = threadIdx.x & 63;
  int bc = blockIdx.x * 4 + w;
  float f = fire[bc * 64 + lane];
  float tot = f;
#pragma unroll
  for (int d = 1; d < 64; d <<= 1) tot += __shfl_xor(tot, d);
  float nf = f / (tot + EPS_F);
  // bitonic sort, descending
  float v = nf;
#pragma unroll
  for (int k = 2; k <= 64; k <<= 1) {
#pragma unroll
    for (int j = 32; j > 0; j >>= 1) {
      if (j >= k) continue;
      float o = __shfl_xor(v, j);
      bool lower = (lane & j) == 0;
      bool desc = (lane & k) == 0;
      float mn = fminf(v, o), mx = fmaxf(v, o);
      v = (desc == lower) ? mx : mn;
    }
  }
  // inclusive scan
  float cs = v;
#pragma unroll
  for (int d = 1; d < 64; d <<= 1) {
    float t = __shfl_up(cs, d);
    if (lane >= d) cs += t;
  }
  float err = cs - tau;
  if (err < 0.f) err = 1.0f;
  float mn = err;
#pragma unroll
  for (int d = 1; d < 64; d <<= 1) mn = fminf(mn, __shfl_xor(mn, d));
  unsigned long long ball = __ballot(err == mn);
  int idx = __ffsll(ball) - 1;
  float thresh = __shfl(v, idx);
  float keep = (nf >= thresh) ? nf : 0.0f;
  float tot2 = keep;
#pragma unroll
  for (int d = 1; d < 64; d <<= 1) tot2 += __shfl_xor(tot2, d);
  nfs[bc * 64 + lane] = keep / (tot2 + EPS_F);
}

// ---------------- pred: sum_r nfs * (x@Wv_r^T + bv_r), atomic fp32 accumulate ----------------
__global__ __launch_bounds__(256) void k_pred(
    const unsigned short* __restrict__ xh, const unsigned short* __restrict__ wvh,
    const float* __restrict__ bv, const float* __restrict__ nfs,
    float* __restrict__ pred) {
  __shared__ unsigned short Al[64 * 256];
  __shared__ unsigned short Bl[256 * 64];
  __shared__ float nl[64][8];
  const int w = threadIdx.x >> 6, lane = threadIdx.x & 63;
  const int cl = lane & 15, kg = lane >> 4;
  const int bc0 = blockIdx.y * 64;
  const int rg0 = blockIdx.x * 8;
#pragma unroll
  for (int j = 0; j < 8; ++j) {
    int s = w * 8 + j;
    int c = s * 64 + lane;
    int row = c >> 5, ko = (c & 31) * 8;
    gload16(xh + (bc0 + row) * 256 + ko, Al + s * 512);
  }
  for (int t = threadIdx.x; t < 512; t += 256) {
    int row = t >> 3, rr = t & 7;
    nl[row][rr] = nfs[(bc0 + row) * 64 + rg0 + rr];
  }
  f32x4 pacc[4][4];
#pragma unroll
  for (int i = 0; i < 4; ++i)
#pragma unroll
    for (int j = 0; j < 4; ++j) pacc[i][j] = (f32x4){0.f, 0.f, 0.f, 0.f};
  for (int rr = 0; rr < 8; ++rr) {
    const int r = rg0 + rr;
    const unsigned short* wb = wvh + r * 65536;
    f32x4 acc[4][4];
#pragma unroll
    for (int i = 0; i < 4; ++i)
#pragma unroll
      for (int j = 0; j < 4; ++j) acc[i][j] = (f32x4){0.f, 0.f, 0.f, 0.f};
#pragma unroll
    for (int ks = 0; ks < 4; ++ks) {
#pragma unroll
      for (int j = 0; j < 8; ++j) {
        int s = w * 8 + j;
        int c = s * 64 + lane;
        int row = c >> 3, ko = (c & 7) * 8;
        gload16(wb + row * 256 + ks * 64 + ko, Bl + s * 512);
      }
      __syncthreads();
#pragma unroll
      for (int kk = 0; kk < 2; ++kk) {
        half8 a[4], b[4];
        int ka = ks * 64 + kk * 32 + kg * 8;
        int kb = kk * 32 + kg * 8;
#pragma unroll
        for (int i = 0; i < 4; ++i)
          a[i] = *(const half8*)(Al + (i * 16 + cl) * 256 + ka);
#pragma unroll
        for (int j = 0; j < 4; ++j)
          b[j] = *(const half8*)(Bl + (w * 64 + j * 16 + cl) * 64 + kb);
#pragma unroll
        for (int i = 0; i < 4; ++i)
#pragma unroll
          for (int j = 0; j < 4; ++j)
            acc[i][j] = __builtin_amdgcn_mfma_f32_16x16x32_f16(a[i], b[j], acc[i][j], 0, 0, 0);
      }
      __syncthreads();
    }
    float bvv[4];
#pragma unroll
    for (int j = 0; j < 4; ++j) bvv[j] = bv[r * 256 + w * 64 + j * 16 + cl];
#pragma unroll
    for (int i = 0; i < 4; ++i)
#pragma unroll
      for (int q = 0; q < 4; ++q) {
        float fct = nl[i * 16 + kg * 4 + q][rr];
#pragma unroll
        for (int j = 0; j < 4; ++j)
          pacc[i][j][q] += fct * (acc[i][j][q] + bvv[j]);
      }
  }
#pragma unroll
  for (int i = 0; i < 4; ++i)
#pragma unroll
    for (int j = 0; j < 4; ++j)
#pragma unroll
      for (int q = 0; q < 4; ++q)
        atomicAdd(&pred[(bc0 + i * 16 + kg * 4 + q) * 256 + (w * 64 + j * 16 + cl)],
                  pacc[i][j][q]);
}

// ---------------- pred f32 -> f16 ----------------
__global__ __launch_bounds__(256) void k_p2h(const float* __restrict__ pred,
                                             unsigned short* __restrict__ ph) {
  int g = (blockIdx.x * 256 + threadIdx.x) * 4;
  float4 v = *(const float4*)(pred + g);
  ushort4 h;
  h.x = f2h(v.x); h.y = f2h(v.y); h.z = f2h(v.z); h.w = f2h(v.w);
  *(ushort4*)(ph + g) = h;
}

// ---------------- out = pred@Wo^T + bo, store transposed [b][p][c] ----------------
__global__ __launch_bounds__(256) void k_out(
    const unsigned short* __restrict__ ph, const unsigned short* __restrict__ woh,
    const float* __restrict__ bo, float* __restrict__ out) {
  __shared__ unsigned short Al[64 * 256];
  __shared__ unsigned short Bl[256 * 64];
  const int w = threadIdx.x >> 6, lane = threadIdx.x & 63;
  const int cl = lane & 15, kg = lane >> 4;
  const int bc0 = blockIdx.x * 64;
#pragma unroll
  for (int j = 0; j < 8; ++j) {
    int s = w * 8 + j;
    int c = s * 64 + lane;
    int row = c >> 5, ko = (c & 31) * 8;
    gload16(ph + (bc0 + row) * 256 + ko, Al + s * 512);
  }
  f32x4 acc[4][4];
#pragma unroll
  for (int i = 0; i < 4; ++i)
#pragma unroll
    for (int j = 0; j < 4; ++j) acc[i][j] = (f32x4){0.f, 0.f, 0.f, 0.f};
#pragma unroll
  for (int ks = 0; ks < 4; ++ks) {
#pragma unroll
    for (int j = 0; j < 8; ++j) {
      int s = w * 8 + j;
      int c = s * 64 + lane;
      int row = c >> 3, ko = (c & 7) * 8;
      gload16(woh + row * 256 + ks * 64 + ko, Bl + s * 512);
    }
    __syncthreads();
#pragma unroll
    for (int kk = 0; kk < 2; ++kk) {
      half8 a[4], b[4];
      int ka = ks * 64 + kk * 32 + kg * 8;
      int kb = kk * 32 + kg * 8;
#pragma unroll
      for (int i = 0; i < 4; ++i)
        a[i] = *(const half8*)(Al + (i * 16 + cl) * 256 + ka);
#pragma unroll
      for (int j = 0; j < 4; ++j)
        b[j] = *(const half8*)(Bl + (w * 64 + j * 16 + cl) * 64 + kb);
#pragma unroll
      for (int i = 0; i < 4; ++i)
#pragma unroll
        for (int j = 0; j < 4; ++j)
          acc[i][j] = __builtin_amdgcn_mfma_f32_16x16x32_f16(a[i], b[j], acc[i][j], 0, 0, 0);
    }
    __syncthreads();
  }
#pragma unroll
  for (int j = 0; j < 4; ++j) {
    int p = w * 64 + j * 16 + cl;
    float bov = bo[p];
#pragma unroll
    for (int i = 0; i < 4; ++i)
#pragma unroll
      for (int q = 0; q < 4; ++q) {
        int bc = bc0 + i * 16 + kg * 4 + q;
        int b = bc >> 9, c = bc & 511;
        out[b * 131072 + p * 512 + c] = acc[i][j][q] + bov;
      }
  }
}

// ---------------- finalize loss ----------------
__global__ __launch_bounds__(256) void k_final(
    const float* __restrict__ bq, const float* __restrict__ bk,
    const float* __restrict__ bv, const float* __restrict__ bo,
    const float* __restrict__ acc, float* __restrict__ loss_out) {
  __shared__ float r[4][4];
  float sbk = 0.f, sbv = 0.f, sbq = 0.f, sbo = 0.f;
  for (int i = threadIdx.x; i < 16384; i += 256) {
    sbk += fabsf(bk[i]);
    sbv += fabsf(bv[i]);
  }
  {
    float a = bq[threadIdx.x];
    sbq = a * a;
    float b = bo[threadIdx.x];
    sbo = b * b;
  }
  int lane = threadIdx.x & 63, w = threadIdx.x >> 6;
#pragma unroll
  for (int d = 1; d < 64; d <<= 1) {
    sbk += __shfl_xor(sbk, d);
    sbv += __shfl_xor(sbv, d);
    sbq += __shfl_xor(sbq, d);
    sbo += __shfl_xor(sbo, d);
  }
  if (lane == 0) { r[w][0] = sbk; r[w][1] = sbv; r[w][2] = sbq; r[w][3] = sbo; }
  __syncthreads();
  if (threadIdx.x == 0) {
    float tbk = r[0][0] + r[1][0] + r[2][0] + r[3][0];
    float tbv = r[0][1] + r[1][1] + r[2][1] + r[3][1];
    float tbq = r[0][2] + r[1][2] + r[2][2] + r[3][2];
    float tbo = r[0][3] + r[1][3] + r[2][3] + r[3][3];
    float loss = 0.01f * (sqrtf(acc[0]) + sqrtf(tbq) + sqrtf(tbo)) +
                 0.001f * (acc[1] + tbk + acc[2] + tbv);
    *loss_out = loss;
  }
}

extern "C" void kernel_launch(void* const* d_in, const int* in_sizes, int n_in,
                              void* d_out, int out_size, void* d_ws, size_t ws_size,
                              hipStream_t stream) {
  const float* in    = (const float*)d_in[0];
  const float* Wq    = (const float*)d_in[1];
  const float* bq    = (const float*)d_in[2];
  const float* Wk    = (const float*)d_in[3];
  const float* bk    = (const float*)d_in[4];
  const float* Wv    = (const float*)d_in[5];
  const float* bv    = (const float*)d_in[6];
  const float* Wo    = (const float*)d_in[7];
  const float* bo    = (const float*)d_in[8];
  const float* sigma = (const float*)d_in[9];
  float* out = (float*)d_out;

  char* ws = (char*)d_ws;
  unsigned short* xh  = (unsigned short*)(ws);                          // 2MB  [4096][256] f16
  unsigned short* wdh = (unsigned short*)(ws + (2u << 20));             // 8MB  [16384][256] f16
  unsigned short* wvh = (unsigned short*)(ws + (10u << 20));            // 8MB
  unsigned short* woh = (unsigned short*)(ws + (18u << 20));            // 128KB [256][256] f16
  unsigned short* ph  = (unsigned short*)(ws + (19u << 20));            // 2MB  [4096][256] f16
  float* bdiff = (float*)(ws + (21u << 20));                            // 64KB
  float* rsig  = (float*)(ws + (21u << 20) + 65536);                    // 64KB
  float* fire  = (float*)(ws + (22u << 20));                            // 1MB [4096][64]
  float* nfs   = (float*)(ws + (23u << 20));                            // 1MB
  float* pred  = (float*)(ws + (24u << 20));                            // 4MB [4096][256] f32
  float* acc   = (float*)(ws + (28u << 20));                            // 16B

  hipMemsetAsync(pred, 0, 4u << 20, stream);
  hipMemsetAsync(acc, 0, 256, stream);

  k_prep_x<<<dim3(16, 8, 8), 256, 0, stream>>>(in, xh);
  k_prep_w<<<4096, 256, 0, stream>>>(Wq, Wk, Wv, Wo, bq, bk, sigma,
                                     wdh, wvh, woh, bdiff, rsig, acc);
  k_wqwo<<<256, 256, 0, stream>>>(Wq, Wo, acc);
  k_fire<<<dim3(8, 64), 256, 0, stream>>>(xh, wdh, bdiff, rsig, fire);
  const float tau = (float)(0.9 * pow(1.0 / (64.0 + (double)EPS_F), 1.0 / 256.0));
  k_mask<<<1024, 256, 0, stream>>>(fire, nfs, tau);
  k_pred<<<dim3(8, 64), 256, 0, stream>>>(xh, wvh, bv, nfs, pred);
  k_p2h<<<1024, 256, 0, stream>>>(pred, ph);
  k_out<<<64, 256, 0, stream>>>(ph, woh, bo, out);
  k_final<<<1, 256, 0, stream>>>(bq, bk, bv, bo, acc, out + 1048576);
}

// Round 2
// 270.511 us; speedup vs baseline: 1.3306x; 1.3306x over previous
//
#include <hip/hip_runtime.h>
#include <math.h>

#define EPS_F 1.1754943508222875e-38f

typedef __attribute__((ext_vector_type(8))) _Float16 half8;
typedef __attribute__((ext_vector_type(4))) float f32x4;
typedef __attribute__((ext_vector_type(8))) unsigned short ushort8;

__device__ __forceinline__ unsigned short f2h(float f) {
  _Float16 h = (_Float16)f;
  return __builtin_bit_cast(unsigned short, h);
}
__device__ __forceinline__ float h2f(unsigned short u) {
  return (float)__builtin_bit_cast(_Float16, u);
}

// async global->LDS, 16B/lane; LDS dest = wave-uniform base + lane*16
__device__ __forceinline__ void gload16(const void* g, void* l) {
  __builtin_amdgcn_global_load_lds(
      (const __attribute__((address_space(1))) void*)g,
      (__attribute__((address_space(3))) void*)l, 16, 0, 0);
}

// ---------------- prep: x transpose + f16 convert ----------------
__global__ __launch_bounds__(256) void k_prep_x(const float* __restrict__ in,
                                                unsigned short* __restrict__ x) {
  __shared__ float t[32][33];
  int c0 = blockIdx.x * 32, p0 = blockIdx.y * 32, b = blockIdx.z;
  int tx = threadIdx.x & 31, ty = threadIdx.x >> 5;
#pragma unroll
  for (int i = ty; i < 32; i += 8)
    t[i][tx] = in[(b * 256 + p0 + i) * 512 + c0 + tx];
  __syncthreads();
#pragma unroll
  for (int i = ty; i < 32; i += 8)
    x[(b * 512 + c0 + i) * 256 + p0 + tx] = f2h(t[tx][i]);
}

// ---------------- prep weights + L1 sums ----------------
__global__ __launch_bounds__(256) void k_prep_w(
    const float* __restrict__ Wq, const float* __restrict__ Wk,
    const float* __restrict__ Wv, const float* __restrict__ Wo,
    const float* __restrict__ bq, const float* __restrict__ bk,
    const float* __restrict__ sigma,
    unsigned short* __restrict__ wd, unsigned short* __restrict__ wvh,
    unsigned short* __restrict__ woh, float* __restrict__ bdiff,
    float* __restrict__ rsig, float* __restrict__ acc) {
  __shared__ float r1[4], r2[4];
  int gid = blockIdx.x * 256 + threadIdx.x;
  int i4 = gid * 4;
  int rm = i4 >> 8, p = i4 & 255, m = rm & 255;
  const float4 wk = *(const float4*)(Wk + i4);
  const float4 wv = *(const float4*)(Wv + i4);
  const float4 wq = *(const float4*)(Wq + m * 256 + p);
  ushort4 d;
  d.x = f2h(wq.x - wk.x); d.y = f2h(wq.y - wk.y);
  d.z = f2h(wq.z - wk.z); d.w = f2h(wq.w - wk.w);
  *(ushort4*)(wd + i4) = d;
  ushort4 vv;
  vv.x = f2h(wv.x); vv.y = f2h(wv.y); vv.z = f2h(wv.z); vv.w = f2h(wv.w);
  *(ushort4*)(wvh + i4) = vv;
  float ak = fabsf(wk.x) + fabsf(wk.y) + fabsf(wk.z) + fabsf(wk.w);
  float av = fabsf(wv.x) + fabsf(wv.y) + fabsf(wv.z) + fabsf(wv.w);
  if (gid < 16384) {
    bdiff[gid] = bq[gid & 255] - bk[gid];
    rsig[gid] = 1.0f / (sigma[gid] + EPS_F);
  }
  if (gid < 65536) woh[gid] = f2h(Wo[gid]);
  int lane = threadIdx.x & 63, w = threadIdx.x >> 6;
#pragma unroll
  for (int dlt = 1; dlt < 64; dlt <<= 1) {
    ak += __shfl_xor(ak, dlt);
    av += __shfl_xor(av, dlt);
  }
  if (lane == 0) { r1[w] = ak; r2[w] = av; }
  __syncthreads();
  if (threadIdx.x == 0) {
    atomicAdd(acc + 1, r1[0] + r1[1] + r1[2] + r1[3]);
    atomicAdd(acc + 2, r2[0] + r2[1] + r2[2] + r2[3]);
  }
}

// ---------------- loss: ||Wq@Wo - I||^2 partial ----------------
__global__ __launch_bounds__(256) void k_wqwo(const float* __restrict__ Wq,
                                              const float* __restrict__ Wo,
                                              float* __restrict__ acc) {
  __shared__ float wq[256];
  __shared__ float red[4];
  int i = blockIdx.x, j = threadIdx.x;
  wq[j] = Wq[i * 256 + j];
  __syncthreads();
  float s = 0.f;
#pragma unroll 8
  for (int p = 0; p < 256; ++p) s = fmaf(wq[p], Wo[p * 256 + j], s);
  float d = s - (i == j ? 1.0f : 0.0f);
  float x = d * d;
#pragma unroll
  for (int dd = 1; dd < 64; dd <<= 1) x += __shfl_xor(x, dd);
  if ((j & 63) == 0) red[j >> 6] = x;
  __syncthreads();
  if (j == 0) atomicAdd(acc + 0, red[0] + red[1] + red[2] + red[3]);
}

// ============ fire: S = x@Wd^T, fire_s[bc][r] = sum_m ((S+bd)*rs)^2 ============
// grid (8 rg, 32 bc), 512 thr (8 waves 2x4), tile 128bc x 256m, 2-phase dbuf B
__global__ __launch_bounds__(512) void k_fire(
    const unsigned short* __restrict__ xh, const unsigned short* __restrict__ wd,
    const float* __restrict__ bdiff, const float* __restrict__ rsig,
    float* __restrict__ fire_s) {
  __shared__ unsigned short Al[128 * 256];   // 64KB, swizzled
  __shared__ unsigned short Bl[2][256 * 64]; // 2x32KB, swizzled
  __shared__ float red[4][128];
  const int tid = threadIdx.x;
  const int w = tid >> 6, lane = tid & 63;
  const int wr = w >> 2, wc = w & 3, cl = lane & 15, kg = lane >> 4;
  const int bc0 = blockIdx.y * 128, rg0 = blockIdx.x * 8;

  // stage A once (swizzled source -> linear LDS == swizzled logical layout)
#pragma unroll
  for (int j = 0; j < 8; ++j) {
    int s = w * 8 + j;
    int C = s * 64 + lane;
    int row = C >> 5, c = C & 31;
    gload16(xh + (bc0 + row) * 256 + ((c ^ (row & 7)) << 3), Al + s * 512);
  }
  // stage B buf0 (r=rg0, ks=0)
#pragma unroll
  for (int j = 0; j < 4; ++j) {
    int s = w * 4 + j;
    int C = s * 64 + lane;
    int n = C >> 3, c = C & 7;
    gload16(wd + (size_t)rg0 * 65536 + n * 256 + ((c ^ (n & 7)) << 3),
            Bl[0] + s * 512);
  }
  __syncthreads();

  for (int rr = 0; rr < 8; ++rr) {
    const int r = rg0 + rr;
    f32x4 acc[4][4];
#pragma unroll
    for (int i = 0; i < 4; ++i)
#pragma unroll
      for (int j = 0; j < 4; ++j) acc[i][j] = (f32x4){0.f, 0.f, 0.f, 0.f};

    for (int ks = 0; ks < 4; ++ks) {
      int t = rr * 4 + ks;
      if (t < 31) {  // prefetch next B stage into alt buffer
        int tn = t + 1;
        const unsigned short* wb =
            wd + (size_t)(rg0 + (tn >> 2)) * 65536 + (tn & 3) * 64;
        unsigned short* dst = Bl[tn & 1];
#pragma unroll
        for (int j = 0; j < 4; ++j) {
          int s = w * 4 + j;
          int C = s * 64 + lane;
          int n = C >> 3, c = C & 7;
          gload16(wb + n * 256 + ((c ^ (n & 7)) << 3), dst + s * 512);
        }
      }
      const unsigned short* Bc = Bl[t & 1];
#pragma unroll
      for (int kk = 0; kk < 2; ++kk) {
        half8 a[4], b[4];
        int k0 = ks * 64 + kk * 32 + kg * 8;
        int kl = kk * 32 + kg * 8;
#pragma unroll
        for (int i = 0; i < 4; ++i) {
          int row = wr * 64 + i * 16 + cl;
          a[i] = *(const half8*)(Al + row * 256 + (((k0 >> 3) ^ (row & 7)) << 3));
        }
#pragma unroll
        for (int j = 0; j < 4; ++j) {
          int n = wc * 64 + j * 16 + cl;
          b[j] = *(const half8*)(Bc + n * 64 + (((kl >> 3) ^ (n & 7)) << 3));
        }
#pragma unroll
        for (int i = 0; i < 4; ++i)
#pragma unroll
          for (int j = 0; j < 4; ++j)
            acc[i][j] = __builtin_amdgcn_mfma_f32_16x16x32_f16(a[i], b[j], acc[i][j], 0, 0, 0);
      }
      __syncthreads();
    }
    // epilogue: rowsum over this wave's 64 cols of ((acc+bd)*rs)^2
    float rowsum[4][4];
#pragma unroll
    for (int i = 0; i < 4; ++i)
#pragma unroll
      for (int q = 0; q < 4; ++q) rowsum[i][q] = 0.f;
#pragma unroll
    for (int j = 0; j < 4; ++j) {
      int mi = r * 256 + wc * 64 + j * 16 + cl;
      float bd = bdiff[mi], rs = rsig[mi];
#pragma unroll
      for (int i = 0; i < 4; ++i)
#pragma unroll
        for (int q = 0; q < 4; ++q) {
          float t2 = (acc[i][j][q] + bd) * rs;
          rowsum[i][q] += t2 * t2;
        }
    }
#pragma unroll
    for (int dlt = 1; dlt < 16; dlt <<= 1)
#pragma unroll
      for (int i = 0; i < 4; ++i)
#pragma unroll
        for (int q = 0; q < 4; ++q) rowsum[i][q] += __shfl_xor(rowsum[i][q], dlt);
    if (cl == 0) {
#pragma unroll
      for (int i = 0; i < 4; ++i)
#pragma unroll
        for (int q = 0; q < 4; ++q)
          red[wc][wr * 64 + i * 16 + kg * 4 + q] = rowsum[i][q];
    }
    __syncthreads();
    if (tid < 128)
      fire_s[(size_t)(bc0 + tid) * 64 + r] =
          red[0][tid] + red[1][tid] + red[2][tid] + red[3][tid];
    __syncthreads();
  }
}

// ---------------- mask: top-p over 64 rules; computes exp here ----------------
__global__ __launch_bounds__(256) void k_mask(const float* __restrict__ fire_s,
                                              float* __restrict__ nfs, float tau) {
  int w = threadIdx.x >> 6, lane = threadIdx.x & 63;
  int bc = blockIdx.x * 4 + w;
  float f = expf(-0.001953125f * fire_s[bc * 64 + lane]) + EPS_F;
  float tot = f;
#pragma unroll
  for (int d = 1; d < 64; d <<= 1) tot += __shfl_xor(tot, d);
  float nf = f / (tot + EPS_F);
  float v = nf;
#pragma unroll
  for (int k = 2; k <= 64; k <<= 1) {
#pragma unroll
    for (int j = 32; j > 0; j >>= 1) {
      if (j >= k) continue;
      float o = __shfl_xor(v, j);
      bool lower = (lane & j) == 0;
      bool desc = (lane & k) == 0;
      float mn = fminf(v, o), mx = fmaxf(v, o);
      v = (desc == lower) ? mx : mn;
    }
  }
  float cs = v;
#pragma unroll
  for (int d = 1; d < 64; d <<= 1) {
    float t = __shfl_up(cs, d);
    if (lane >= d) cs += t;
  }
  float err = cs - tau;
  if (err < 0.f) err = 1.0f;
  float mn = err;
#pragma unroll
  for (int d = 1; d < 64; d <<= 1) mn = fminf(mn, __shfl_xor(mn, d));
  unsigned long long ball = __ballot(err == mn);
  int idx = __ffsll(ball) - 1;
  float thresh = __shfl(v, idx);
  float keep = (nf >= thresh) ? nf : 0.0f;
  float tot2 = keep;
#pragma unroll
  for (int d = 1; d < 64; d <<= 1) tot2 += __shfl_xor(tot2, d);
  nfs[bc * 64 + lane] = keep / (tot2 + EPS_F);
}

// ============ pred: sum_r nfs*(x@Wv_r^T + bv_r) -> f16 partials (4 rgroups) ============
// grid (4 rg, 64 bc), 512 thr, tile 64bc x 256m, 16 r per block
__global__ __launch_bounds__(512) void k_pred(
    const unsigned short* __restrict__ xh, const unsigned short* __restrict__ wvh,
    const float* __restrict__ bv, const float* __restrict__ nfs,
    unsigned short* __restrict__ pp) {
  __shared__ unsigned short Al[64 * 256];    // 32KB
  __shared__ unsigned short Bl[2][256 * 64]; // 64KB
  __shared__ float nl[64][16];               // 4KB
  const int tid = threadIdx.x;
  const int w = tid >> 6, lane = tid & 63;
  const int wr = w >> 2, wc = w & 3, cl = lane & 15, kg = lane >> 4;
  const int bc0 = blockIdx.y * 64, rg0 = blockIdx.x * 16;

#pragma unroll
  for (int j = 0; j < 4; ++j) {
    int s = w * 4 + j;
    int C = s * 64 + lane;
    int row = C >> 5, c = C & 31;
    gload16(xh + (bc0 + row) * 256 + ((c ^ (row & 7)) << 3), Al + s * 512);
  }
#pragma unroll
  for (int j = 0; j < 4; ++j) {
    int s = w * 4 + j;
    int C = s * 64 + lane;
    int n = C >> 3, c = C & 7;
    gload16(wvh + (size_t)rg0 * 65536 + n * 256 + ((c ^ (n & 7)) << 3),
            Bl[0] + s * 512);
  }
  for (int t = tid; t < 1024; t += 512) {
    int row = t >> 4, rr = t & 15;
    nl[row][rr] = nfs[(bc0 + row) * 64 + rg0 + rr];
  }
  __syncthreads();

  f32x4 pacc[2][4];
#pragma unroll
  for (int i = 0; i < 2; ++i)
#pragma unroll
    for (int j = 0; j < 4; ++j) pacc[i][j] = (f32x4){0.f, 0.f, 0.f, 0.f};

  for (int rr = 0; rr < 16; ++rr) {
    const int r = rg0 + rr;
    f32x4 acc[2][4];
#pragma unroll
    for (int i = 0; i < 2; ++i)
#pragma unroll
      for (int j = 0; j < 4; ++j) acc[i][j] = (f32x4){0.f, 0.f, 0.f, 0.f};

    for (int ks = 0; ks < 4; ++ks) {
      int t = rr * 4 + ks;
      if (t < 63) {
        int tn = t + 1;
        const unsigned short* wb =
            wvh + (size_t)(rg0 + (tn >> 2)) * 65536 + (tn & 3) * 64;
        unsigned short* dst = Bl[tn & 1];
#pragma unroll
        for (int j = 0; j < 4; ++j) {
          int s = w * 4 + j;
          int C = s * 64 + lane;
          int n = C >> 3, c = C & 7;
          gload16(wb + n * 256 + ((c ^ (n & 7)) << 3), dst + s * 512);
        }
      }
      const unsigned short* Bc = Bl[t & 1];
#pragma unroll
      for (int kk = 0; kk < 2; ++kk) {
        half8 a[2], b[4];
        int k0 = ks * 64 + kk * 32 + kg * 8;
        int kl = kk * 32 + kg * 8;
#pragma unroll
        for (int i = 0; i < 2; ++i) {
          int row = wr * 32 + i * 16 + cl;
          a[i] = *(const half8*)(Al + row * 256 + (((k0 >> 3) ^ (row & 7)) << 3));
        }
#pragma unroll
        for (int j = 0; j < 4; ++j) {
          int n = wc * 64 + j * 16 + cl;
          b[j] = *(const half8*)(Bc + n * 64 + (((kl >> 3) ^ (n & 7)) << 3));
        }
#pragma unroll
        for (int i = 0; i < 2; ++i)
#pragma unroll
          for (int j = 0; j < 4; ++j)
            acc[i][j] = __builtin_amdgcn_mfma_f32_16x16x32_f16(a[i], b[j], acc[i][j], 0, 0, 0);
      }
      __syncthreads();
    }
    // accumulate nfs-weighted
    float bvv[4];
#pragma unroll
    for (int j = 0; j < 4; ++j) bvv[j] = bv[r * 256 + wc * 64 + j * 16 + cl];
#pragma unroll
    for (int i = 0; i < 2; ++i)
#pragma unroll
      for (int q = 0; q < 4; ++q) {
        float fct = nl[wr * 32 + i * 16 + kg * 4 + q][rr];
#pragma unroll
        for (int j = 0; j < 4; ++j)
          pacc[i][j][q] += fct * (acc[i][j][q] + bvv[j]);
      }
  }
  // store f16 partial for this r-group
  unsigned short* base = pp + (size_t)blockIdx.x * 1048576;
#pragma unroll
  for (int i = 0; i < 2; ++i)
#pragma unroll
    for (int q = 0; q < 4; ++q) {
      int row = bc0 + wr * 32 + i * 16 + kg * 4 + q;
#pragma unroll
      for (int j = 0; j < 4; ++j)
        base[(size_t)row * 256 + wc * 64 + j * 16 + cl] = f2h(pacc[i][j][q]);
    }
}

// ---------------- reduce 4 f16 partials -> ph (f16) ----------------
__global__ __launch_bounds__(256) void k_p2h(const unsigned short* __restrict__ pp,
                                             unsigned short* __restrict__ ph) {
  int g = (blockIdx.x * 256 + threadIdx.x) * 8;
  float s[8];
#pragma unroll
  for (int e = 0; e < 8; ++e) s[e] = 0.f;
#pragma unroll
  for (int rg = 0; rg < 4; ++rg) {
    ushort8 v = *(const ushort8*)(pp + (size_t)rg * 1048576 + g);
#pragma unroll
    for (int e = 0; e < 8; ++e) s[e] += h2f(v[e]);
  }
  ushort8 o;
#pragma unroll
  for (int e = 0; e < 8; ++e) o[e] = f2h(s[e]);
  *(ushort8*)(ph + g) = o;
}

// ============ out^T: C[p][bc] = Wo @ pred^T, store out[b][p][c] ============
// grid (2 p-tiles, 16 bc-tiles), 512 thr, tile 128p x 256bc
__global__ __launch_bounds__(512) void k_out(
    const unsigned short* __restrict__ ph, const unsigned short* __restrict__ woh,
    const float* __restrict__ bo, float* __restrict__ out) {
  __shared__ unsigned short Al[128 * 256];
  __shared__ unsigned short Bl[2][256 * 64];
  const int tid = threadIdx.x;
  const int w = tid >> 6, lane = tid & 63;
  const int wr = w >> 2, wc = w & 3, cl = lane & 15, kg = lane >> 4;
  const int p0 = blockIdx.x * 128, bc1 = blockIdx.y;

#pragma unroll
  for (int j = 0; j < 8; ++j) {
    int s = w * 8 + j;
    int C = s * 64 + lane;
    int row = C >> 5, c = C & 31;
    gload16(woh + (p0 + row) * 256 + ((c ^ (row & 7)) << 3), Al + s * 512);
  }
#pragma unroll
  for (int j = 0; j < 4; ++j) {
    int s = w * 4 + j;
    int C = s * 64 + lane;
    int n = C >> 3, c = C & 7;
    gload16(ph + (size_t)(bc1 * 256 + n) * 256 + ((c ^ (n & 7)) << 3),
            Bl[0] + s * 512);
  }
  __syncthreads();

  f32x4 acc[4][4];
#pragma unroll
  for (int i = 0; i < 4; ++i)
#pragma unroll
    for (int j = 0; j < 4; ++j) acc[i][j] = (f32x4){0.f, 0.f, 0.f, 0.f};

  for (int ks = 0; ks < 4; ++ks) {
    if (ks < 3) {
      int ksn = ks + 1;
      unsigned short* dst = Bl[ksn & 1];
#pragma unroll
      for (int j = 0; j < 4; ++j) {
        int s = w * 4 + j;
        int C = s * 64 + lane;
        int n = C >> 3, c = C & 7;
        gload16(ph + (size_t)(bc1 * 256 + n) * 256 + ksn * 64 + ((c ^ (n & 7)) << 3),
                dst + s * 512);
      }
    }
    const unsigned short* Bc = Bl[ks & 1];
#pragma unroll
    for (int kk = 0; kk < 2; ++kk) {
      half8 a[4], b[4];
      int k0 = ks * 64 + kk * 32 + kg * 8;
      int kl = kk * 32 + kg * 8;
#pragma unroll
      for (int i = 0; i < 4; ++i) {
        int row = wr * 64 + i * 16 + cl;
        a[i] = *(const half8*)(Al + row * 256 + (((k0 >> 3) ^ (row & 7)) << 3));
      }
#pragma unroll
      for (int j = 0; j < 4; ++j) {
        int n = wc * 64 + j * 16 + cl;
        b[j] = *(const half8*)(Bc + n * 64 + (((kl >> 3) ^ (n & 7)) << 3));
      }
#pragma unroll
      for (int i = 0; i < 4; ++i)
#pragma unroll
        for (int j = 0; j < 4; ++j)
          acc[i][j] = __builtin_amdgcn_mfma_f32_16x16x32_f16(a[i], b[j], acc[i][j], 0, 0, 0);
    }
    __syncthreads();
  }
  int b = bc1 >> 1, c0 = (bc1 & 1) * 256;
#pragma unroll
  for (int i = 0; i < 4; ++i)
#pragma unroll
    for (int q = 0; q < 4; ++q) {
      int p = p0 + wr * 64 + i * 16 + kg * 4 + q;
      float bov = bo[p];
#pragma unroll
      for (int j = 0; j < 4; ++j) {
        int col = wc * 64 + j * 16 + cl;
        out[(size_t)b * 131072 + (size_t)p * 512 + c0 + col] = acc[i][j][q] + bov;
      }
    }
}

// ---------------- finalize loss ----------------
__global__ __launch_bounds__(256) void k_final(
    const float* __restrict__ bq, const float* __restrict__ bk,
    const float* __restrict__ bv, const float* __restrict__ bo,
    const float* __restrict__ acc, float* __restrict__ loss_out) {
  __shared__ float r[4][4];
  float sbk = 0.f, sbv = 0.f, sbq = 0.f, sbo = 0.f;
  for (int i = threadIdx.x; i < 16384; i += 256) {
    sbk += fabsf(bk[i]);
    sbv += fabsf(bv[i]);
  }
  {
    float a = bq[threadIdx.x];
    sbq = a * a;
    float b = bo[threadIdx.x];
    sbo = b * b;
  }
  int lane = threadIdx.x & 63, w = threadIdx.x >> 6;
#pragma unroll
  for (int d = 1; d < 64; d <<= 1) {
    sbk += __shfl_xor(sbk, d);
    sbv += __shfl_xor(sbv, d);
    sbq += __shfl_xor(sbq, d);
    sbo += __shfl_xor(sbo, d);
  }
  if (lane == 0) { r[w][0] = sbk; r[w][1] = sbv; r[w][2] = sbq; r[w][3] = sbo; }
  __syncthreads();
  if (threadIdx.x == 0) {
    float tbk = r[0][0] + r[1][0] + r[2][0] + r[3][0];
    float tbv = r[0][1] + r[1][1] + r[2][1] + r[3][1];
    float tbq = r[0][2] + r[1][2] + r[2][2] + r[3][2];
    float tbo = r[0][3] + r[1][3] + r[2][3] + r[3][3];
    float loss = 0.01f * (sqrtf(acc[0]) + sqrtf(tbq) + sqrtf(tbo)) +
                 0.001f * (acc[1] + tbk + acc[2] + tbv);
    *loss_out = loss;
  }
}

extern "C" void kernel_launch(void* const* d_in, const int* in_sizes, int n_in,
                              void* d_out, int out_size, void* d_ws, size_t ws_size,
                              hipStream_t stream) {
  const float* in    = (const float*)d_in[0];
  const float* Wq    = (const float*)d_in[1];
  const float* bq    = (const float*)d_in[2];
  const float* Wk    = (const float*)d_in[3];
  const float* bk    = (const float*)d_in[4];
  const float* Wv    = (const float*)d_in[5];
  const float* bv    = (const float*)d_in[6];
  const float* Wo    = (const float*)d_in[7];
  const float* bo    = (const float*)d_in[8];
  const float* sigma = (const float*)d_in[9];
  float* out = (float*)d_out;

  char* ws = (char*)d_ws;
  // layout (bytes), total 22.5MB; partial reuses dead wdh region
  unsigned short* xh     = (unsigned short*)(ws);               // 2MB
  unsigned short* woh    = (unsigned short*)(ws + 2097152);     // 128KB
  float*          bdiff  = (float*)(ws + 2228224);              // 64KB
  float*          rsig   = (float*)(ws + 2293760);              // 64KB
  float*          fire_s = (float*)(ws + 2359296);              // 1MB
  float*          nfs    = (float*)(ws + 3407872);              // 1MB
  unsigned short* ph     = (unsigned short*)(ws + 4456448);     // 2MB
  float*          acc    = (float*)(ws + 6553600);              // 256B
  unsigned short* wdh    = (unsigned short*)(ws + 6815744);     // 8MB (dead after k_fire)
  unsigned short* pp     = (unsigned short*)(ws + 6815744);     // 8MB partials (reuse)
  unsigned short* wvh    = (unsigned short*)(ws + 15204352);    // 8MB

  hipMemsetAsync(acc, 0, 256, stream);

  k_prep_x<<<dim3(16, 8, 8), 256, 0, stream>>>(in, xh);
  k_prep_w<<<4096, 256, 0, stream>>>(Wq, Wk, Wv, Wo, bq, bk, sigma,
                                     wdh, wvh, woh, bdiff, rsig, acc);
  k_wqwo<<<256, 256, 0, stream>>>(Wq, Wo, acc);
  k_fire<<<dim3(8, 32), 512, 0, stream>>>(xh, wdh, bdiff, rsig, fire_s);
  const float tau = (float)(0.9 * pow(1.0 / (64.0 + (double)EPS_F), 1.0 / 256.0));
  k_mask<<<1024, 256, 0, stream>>>(fire_s, nfs, tau);
  k_pred<<<dim3(4, 64), 512, 0, stream>>>(xh, wvh, bv, nfs, pp);
  k_p2h<<<512, 256, 0, stream>>>(pp, ph);
  k_out<<<dim3(2, 16), 512, 0, stream>>>(ph, woh, bo, out);
  k_final<<<1, 256, 0, stream>>>(bq, bk, bv, bo, acc, out + 1048576);
}

// Round 3
// 168.806 us; speedup vs baseline: 2.1323x; 1.6025x over previous
//
#include <hip/hip_runtime.h>
#include <math.h>

#define EPS_F 1.1754943508222875e-38f

typedef __attribute__((ext_vector_type(8))) _Float16 half8;
typedef __attribute__((ext_vector_type(4))) float f32x4;
typedef __attribute__((ext_vector_type(8))) unsigned short ushort8;

__device__ __forceinline__ unsigned short f2h(float f) {
  _Float16 h = (_Float16)f;
  return __builtin_bit_cast(unsigned short, h);
}
__device__ __forceinline__ float h2f(unsigned short u) {
  return (float)__builtin_bit_cast(_Float16, u);
}

// async global->LDS, 16B/lane; LDS dest = wave-uniform base + lane*16
__device__ __forceinline__ void gload16(const void* g, void* l) {
  __builtin_amdgcn_global_load_lds(
      (const __attribute__((address_space(1))) void*)g,
      (__attribute__((address_space(3))) void*)l, 16, 0, 0);
}

// ---------------- prep: x transpose + f16 convert ----------------
__global__ __launch_bounds__(256) void k_prep_x(const float* __restrict__ in,
                                                unsigned short* __restrict__ x) {
  __shared__ float t[32][33];
  int c0 = blockIdx.x * 32, p0 = blockIdx.y * 32, b = blockIdx.z;
  int tx = threadIdx.x & 31, ty = threadIdx.x >> 5;
#pragma unroll
  for (int i = ty; i < 32; i += 8)
    t[i][tx] = in[(b * 256 + p0 + i) * 512 + c0 + tx];
  __syncthreads();
#pragma unroll
  for (int i = ty; i < 32; i += 8)
    x[(b * 512 + c0 + i) * 256 + p0 + tx] = f2h(t[tx][i]);
}

// ---------------- prep weights + per-block L1 partials (NO atomics) ----------------
__global__ __launch_bounds__(256) void k_prep_w(
    const float* __restrict__ Wq, const float* __restrict__ Wk,
    const float* __restrict__ Wv, const float* __restrict__ Wo,
    const float* __restrict__ bq, const float* __restrict__ bk,
    const float* __restrict__ sigma,
    unsigned short* __restrict__ wd, unsigned short* __restrict__ wvh,
    unsigned short* __restrict__ woh, float* __restrict__ bdiff,
    float* __restrict__ rsig, float* __restrict__ pbk,
    float* __restrict__ pbv) {
  __shared__ float r1[4], r2[4];
  int gid = blockIdx.x * 256 + threadIdx.x;
  int i4 = gid * 4;
  int rm = i4 >> 8, p = i4 & 255, m = rm & 255;
  const float4 wk = *(const float4*)(Wk + i4);
  const float4 wv = *(const float4*)(Wv + i4);
  const float4 wq = *(const float4*)(Wq + m * 256 + p);
  ushort4 d;
  d.x = f2h(wq.x - wk.x); d.y = f2h(wq.y - wk.y);
  d.z = f2h(wq.z - wk.z); d.w = f2h(wq.w - wk.w);
  *(ushort4*)(wd + i4) = d;
  ushort4 vv;
  vv.x = f2h(wv.x); vv.y = f2h(wv.y); vv.z = f2h(wv.z); vv.w = f2h(wv.w);
  *(ushort4*)(wvh + i4) = vv;
  float ak = fabsf(wk.x) + fabsf(wk.y) + fabsf(wk.z) + fabsf(wk.w);
  float av = fabsf(wv.x) + fabsf(wv.y) + fabsf(wv.z) + fabsf(wv.w);
  if (gid < 16384) {
    bdiff[gid] = bq[gid & 255] - bk[gid];
    rsig[gid] = 1.0f / (sigma[gid] + EPS_F);
  }
  if (gid < 65536) woh[gid] = f2h(Wo[gid]);
  int lane = threadIdx.x & 63, w = threadIdx.x >> 6;
#pragma unroll
  for (int dlt = 1; dlt < 64; dlt <<= 1) {
    ak += __shfl_xor(ak, dlt);
    av += __shfl_xor(av, dlt);
  }
  if (lane == 0) { r1[w] = ak; r2[w] = av; }
  __syncthreads();
  if (threadIdx.x == 0) {
    pbk[blockIdx.x] = r1[0] + r1[1] + r1[2] + r1[3];
    pbv[blockIdx.x] = r2[0] + r2[1] + r2[2] + r2[3];
  }
}

// ---------------- loss: ||Wq@Wo - I||^2 per-block partial (NO atomics) ----------------
__global__ __launch_bounds__(256) void k_wqwo(const float* __restrict__ Wq,
                                              const float* __restrict__ Wo,
                                              float* __restrict__ pbw) {
  __shared__ float wq[256];
  __shared__ float red[4];
  int i = blockIdx.x, j = threadIdx.x;
  wq[j] = Wq[i * 256 + j];
  __syncthreads();
  float s = 0.f;
#pragma unroll 8
  for (int p = 0; p < 256; ++p) s = fmaf(wq[p], Wo[p * 256 + j], s);
  float d = s - (i == j ? 1.0f : 0.0f);
  float x = d * d;
#pragma unroll
  for (int dd = 1; dd < 64; dd <<= 1) x += __shfl_xor(x, dd);
  if ((j & 63) == 0) red[j >> 6] = x;
  __syncthreads();
  if (j == 0) pbw[blockIdx.x] = red[0] + red[1] + red[2] + red[3];
}

// ============ fire: S = x@Wd^T, fire_s[bc][r] = sum_m ((S+bd)*rs)^2 ============
__global__ __launch_bounds__(512) void k_fire(
    const unsigned short* __restrict__ xh, const unsigned short* __restrict__ wd,
    const float* __restrict__ bdiff, const float* __restrict__ rsig,
    float* __restrict__ fire_s) {
  __shared__ unsigned short Al[128 * 256];   // 64KB, swizzled
  __shared__ unsigned short Bl[2][256 * 64]; // 2x32KB, swizzled
  __shared__ float red[4][128];
  const int tid = threadIdx.x;
  const int w = tid >> 6, lane = tid & 63;
  const int wr = w >> 2, wc = w & 3, cl = lane & 15, kg = lane >> 4;
  const int bc0 = blockIdx.y * 128, rg0 = blockIdx.x * 8;

#pragma unroll
  for (int j = 0; j < 8; ++j) {
    int s = w * 8 + j;
    int C = s * 64 + lane;
    int row = C >> 5, c = C & 31;
    gload16(xh + (bc0 + row) * 256 + ((c ^ (row & 7)) << 3), Al + s * 512);
  }
#pragma unroll
  for (int j = 0; j < 4; ++j) {
    int s = w * 4 + j;
    int C = s * 64 + lane;
    int n = C >> 3, c = C & 7;
    gload16(wd + (size_t)rg0 * 65536 + n * 256 + ((c ^ (n & 7)) << 3),
            Bl[0] + s * 512);
  }
  __syncthreads();

  for (int rr = 0; rr < 8; ++rr) {
    const int r = rg0 + rr;
    f32x4 acc[4][4];
#pragma unroll
    for (int i = 0; i < 4; ++i)
#pragma unroll
      for (int j = 0; j < 4; ++j) acc[i][j] = (f32x4){0.f, 0.f, 0.f, 0.f};

    for (int ks = 0; ks < 4; ++ks) {
      int t = rr * 4 + ks;
      if (t < 31) {
        int tn = t + 1;
        const unsigned short* wb =
            wd + (size_t)(rg0 + (tn >> 2)) * 65536 + (tn & 3) * 64;
        unsigned short* dst = Bl[tn & 1];
#pragma unroll
        for (int j = 0; j < 4; ++j) {
          int s = w * 4 + j;
          int C = s * 64 + lane;
          int n = C >> 3, c = C & 7;
          gload16(wb + n * 256 + ((c ^ (n & 7)) << 3), dst + s * 512);
        }
      }
      const unsigned short* Bc = Bl[t & 1];
#pragma unroll
      for (int kk = 0; kk < 2; ++kk) {
        half8 a[4], b[4];
        int k0 = ks * 64 + kk * 32 + kg * 8;
        int kl = kk * 32 + kg * 8;
#pragma unroll
        for (int i = 0; i < 4; ++i) {
          int row = wr * 64 + i * 16 + cl;
          a[i] = *(const half8*)(Al + row * 256 + (((k0 >> 3) ^ (row & 7)) << 3));
        }
#pragma unroll
        for (int j = 0; j < 4; ++j) {
          int n = wc * 64 + j * 16 + cl;
          b[j] = *(const half8*)(Bc + n * 64 + (((kl >> 3) ^ (n & 7)) << 3));
        }
#pragma unroll
        for (int i = 0; i < 4; ++i)
#pragma unroll
          for (int j = 0; j < 4; ++j)
            acc[i][j] = __builtin_amdgcn_mfma_f32_16x16x32_f16(a[i], b[j], acc[i][j], 0, 0, 0);
      }
      __syncthreads();
    }
    float rowsum[4][4];
#pragma unroll
    for (int i = 0; i < 4; ++i)
#pragma unroll
      for (int q = 0; q < 4; ++q) rowsum[i][q] = 0.f;
#pragma unroll
    for (int j = 0; j < 4; ++j) {
      int mi = r * 256 + wc * 64 + j * 16 + cl;
      float bd = bdiff[mi], rs = rsig[mi];
#pragma unroll
      for (int i = 0; i < 4; ++i)
#pragma unroll
        for (int q = 0; q < 4; ++q) {
          float t2 = (acc[i][j][q] + bd) * rs;
          rowsum[i][q] += t2 * t2;
        }
    }
#pragma unroll
    for (int dlt = 1; dlt < 16; dlt <<= 1)
#pragma unroll
      for (int i = 0; i < 4; ++i)
#pragma unroll
        for (int q = 0; q < 4; ++q) rowsum[i][q] += __shfl_xor(rowsum[i][q], dlt);
    if (cl == 0) {
#pragma unroll
      for (int i = 0; i < 4; ++i)
#pragma unroll
        for (int q = 0; q < 4; ++q)
          red[wc][wr * 64 + i * 16 + kg * 4 + q] = rowsum[i][q];
    }
    __syncthreads();
    if (tid < 128)
      fire_s[(size_t)(bc0 + tid) * 64 + r] =
          red[0][tid] + red[1][tid] + red[2][tid] + red[3][tid];
    __syncthreads();
  }
}

// ---------------- mask: top-p over 64 rules; computes exp here ----------------
__global__ __launch_bounds__(256) void k_mask(const float* __restrict__ fire_s,
                                              float* __restrict__ nfs, float tau) {
  int w = threadIdx.x >> 6, lane = threadIdx.x & 63;
  int bc = blockIdx.x * 4 + w;
  float f = expf(-0.001953125f * fire_s[bc * 64 + lane]) + EPS_F;
  float tot = f;
#pragma unroll
  for (int d = 1; d < 64; d <<= 1) tot += __shfl_xor(tot, d);
  float nf = f / (tot + EPS_F);
  float v = nf;
#pragma unroll
  for (int k = 2; k <= 64; k <<= 1) {
#pragma unroll
    for (int j = 32; j > 0; j >>= 1) {
      if (j >= k) continue;
      float o = __shfl_xor(v, j);
      bool lower = (lane & j) == 0;
      bool desc = (lane & k) == 0;
      float mn = fminf(v, o), mx = fmaxf(v, o);
      v = (desc == lower) ? mx : mn;
    }
  }
  float cs = v;
#pragma unroll
  for (int d = 1; d < 64; d <<= 1) {
    float t = __shfl_up(cs, d);
    if (lane >= d) cs += t;
  }
  float err = cs - tau;
  if (err < 0.f) err = 1.0f;
  float mn = err;
#pragma unroll
  for (int d = 1; d < 64; d <<= 1) mn = fminf(mn, __shfl_xor(mn, d));
  unsigned long long ball = __ballot(err == mn);
  int idx = __ffsll(ball) - 1;
  float thresh = __shfl(v, idx);
  float keep = (nf >= thresh) ? nf : 0.0f;
  float tot2 = keep;
#pragma unroll
  for (int d = 1; d < 64; d <<= 1) tot2 += __shfl_xor(tot2, d);
  nfs[bc * 64 + lane] = keep / (tot2 + EPS_F);
}

// ============ pred: sum_r nfs*(x@Wv_r^T + bv_r) -> f16 partials (4 rgroups) ============
__global__ __launch_bounds__(512) void k_pred(
    const unsigned short* __restrict__ xh, const unsigned short* __restrict__ wvh,
    const float* __restrict__ bv, const float* __restrict__ nfs,
    unsigned short* __restrict__ pp) {
  __shared__ unsigned short Al[64 * 256];    // 32KB
  __shared__ unsigned short Bl[2][256 * 64]; // 64KB
  __shared__ float nl[64][16];               // 4KB
  const int tid = threadIdx.x;
  const int w = tid >> 6, lane = tid & 63;
  const int wr = w >> 2, wc = w & 3, cl = lane & 15, kg = lane >> 4;
  const int bc0 = blockIdx.y * 64, rg0 = blockIdx.x * 16;

#pragma unroll
  for (int j = 0; j < 4; ++j) {
    int s = w * 4 + j;
    int C = s * 64 + lane;
    int row = C >> 5, c = C & 31;
    gload16(xh + (bc0 + row) * 256 + ((c ^ (row & 7)) << 3), Al + s * 512);
  }
#pragma unroll
  for (int j = 0; j < 4; ++j) {
    int s = w * 4 + j;
    int C = s * 64 + lane;
    int n = C >> 3, c = C & 7;
    gload16(wvh + (size_t)rg0 * 65536 + n * 256 + ((c ^ (n & 7)) << 3),
            Bl[0] + s * 512);
  }
  for (int t = tid; t < 1024; t += 512) {
    int row = t >> 4, rr = t & 15;
    nl[row][rr] = nfs[(bc0 + row) * 64 + rg0 + rr];
  }
  __syncthreads();

  f32x4 pacc[2][4];
#pragma unroll
  for (int i = 0; i < 2; ++i)
#pragma unroll
    for (int j = 0; j < 4; ++j) pacc[i][j] = (f32x4){0.f, 0.f, 0.f, 0.f};

  for (int rr = 0; rr < 16; ++rr) {
    const int r = rg0 + rr;
    f32x4 acc[2][4];
#pragma unroll
    for (int i = 0; i < 2; ++i)
#pragma unroll
      for (int j = 0; j < 4; ++j) acc[i][j] = (f32x4){0.f, 0.f, 0.f, 0.f};

    for (int ks = 0; ks < 4; ++ks) {
      int t = rr * 4 + ks;
      if (t < 63) {
        int tn = t + 1;
        const unsigned short* wb =
            wvh + (size_t)(rg0 + (tn >> 2)) * 65536 + (tn & 3) * 64;
        unsigned short* dst = Bl[tn & 1];
#pragma unroll
        for (int j = 0; j < 4; ++j) {
          int s = w * 4 + j;
          int C = s * 64 + lane;
          int n = C >> 3, c = C & 7;
          gload16(wb + n * 256 + ((c ^ (n & 7)) << 3), dst + s * 512);
        }
      }
      const unsigned short* Bc = Bl[t & 1];
#pragma unroll
      for (int kk = 0; kk < 2; ++kk) {
        half8 a[2], b[4];
        int k0 = ks * 64 + kk * 32 + kg * 8;
        int kl = kk * 32 + kg * 8;
#pragma unroll
        for (int i = 0; i < 2; ++i) {
          int row = wr * 32 + i * 16 + cl;
          a[i] = *(const half8*)(Al + row * 256 + (((k0 >> 3) ^ (row & 7)) << 3));
        }
#pragma unroll
        for (int j = 0; j < 4; ++j) {
          int n = wc * 64 + j * 16 + cl;
          b[j] = *(const half8*)(Bc + n * 64 + (((kl >> 3) ^ (n & 7)) << 3));
        }
#pragma unroll
        for (int i = 0; i < 2; ++i)
#pragma unroll
          for (int j = 0; j < 4; ++j)
            acc[i][j] = __builtin_amdgcn_mfma_f32_16x16x32_f16(a[i], b[j], acc[i][j], 0, 0, 0);
      }
      __syncthreads();
    }
    float bvv[4];
#pragma unroll
    for (int j = 0; j < 4; ++j) bvv[j] = bv[r * 256 + wc * 64 + j * 16 + cl];
#pragma unroll
    for (int i = 0; i < 2; ++i)
#pragma unroll
      for (int q = 0; q < 4; ++q) {
        float fct = nl[wr * 32 + i * 16 + kg * 4 + q][rr];
#pragma unroll
        for (int j = 0; j < 4; ++j)
          pacc[i][j][q] += fct * (acc[i][j][q] + bvv[j]);
      }
  }
  unsigned short* base = pp + (size_t)blockIdx.x * 1048576;
#pragma unroll
  for (int i = 0; i < 2; ++i)
#pragma unroll
    for (int q = 0; q < 4; ++q) {
      int row = bc0 + wr * 32 + i * 16 + kg * 4 + q;
#pragma unroll
      for (int j = 0; j < 4; ++j)
        base[(size_t)row * 256 + wc * 64 + j * 16 + cl] = f2h(pacc[i][j][q]);
    }
}

// ---------------- reduce 4 f16 partials -> ph (f16) ----------------
__global__ __launch_bounds__(256) void k_p2h(const unsigned short* __restrict__ pp,
                                             unsigned short* __restrict__ ph) {
  int g = (blockIdx.x * 256 + threadIdx.x) * 8;
  float s[8];
#pragma unroll
  for (int e = 0; e < 8; ++e) s[e] = 0.f;
#pragma unroll
  for (int rg = 0; rg < 4; ++rg) {
    ushort8 v = *(const ushort8*)(pp + (size_t)rg * 1048576 + g);
#pragma unroll
    for (int e = 0; e < 8; ++e) s[e] += h2f(v[e]);
  }
  ushort8 o;
#pragma unroll
  for (int e = 0; e < 8; ++e) o[e] = f2h(s[e]);
  *(ushort8*)(ph + g) = o;
}

// ============ out^T: C[p][bc] = Wo @ pred^T, store out[b][p][c] ============
__global__ __launch_bounds__(512) void k_out(
    const unsigned short* __restrict__ ph, const unsigned short* __restrict__ woh,
    const float* __restrict__ bo, float* __restrict__ out) {
  __shared__ unsigned short Al[128 * 256];
  __shared__ unsigned short Bl[2][256 * 64];
  const int tid = threadIdx.x;
  const int w = tid >> 6, lane = tid & 63;
  const int wr = w >> 2, wc = w & 3, cl = lane & 15, kg = lane >> 4;
  const int p0 = blockIdx.x * 128, bc1 = blockIdx.y;

#pragma unroll
  for (int j = 0; j < 8; ++j) {
    int s = w * 8 + j;
    int C = s * 64 + lane;
    int row = C >> 5, c = C & 31;
    gload16(woh + (p0 + row) * 256 + ((c ^ (row & 7)) << 3), Al + s * 512);
  }
#pragma unroll
  for (int j = 0; j < 4; ++j) {
    int s = w * 4 + j;
    int C = s * 64 + lane;
    int n = C >> 3, c = C & 7;
    gload16(ph + (size_t)(bc1 * 256 + n) * 256 + ((c ^ (n & 7)) << 3),
            Bl[0] + s * 512);
  }
  __syncthreads();

  f32x4 acc[4][4];
#pragma unroll
  for (int i = 0; i < 4; ++i)
#pragma unroll
    for (int j = 0; j < 4; ++j) acc[i][j] = (f32x4){0.f, 0.f, 0.f, 0.f};

  for (int ks = 0; ks < 4; ++ks) {
    if (ks < 3) {
      int ksn = ks + 1;
      unsigned short* dst = Bl[ksn & 1];
#pragma unroll
      for (int j = 0; j < 4; ++j) {
        int s = w * 4 + j;
        int C = s * 64 + lane;
        int n = C >> 3, c = C & 7;
        gload16(ph + (size_t)(bc1 * 256 + n) * 256 + ksn * 64 + ((c ^ (n & 7)) << 3),
                dst + s * 512);
      }
    }
    const unsigned short* Bc = Bl[ks & 1];
#pragma unroll
    for (int kk = 0; kk < 2; ++kk) {
      half8 a[4], b[4];
      int k0 = ks * 64 + kk * 32 + kg * 8;
      int kl = kk * 32 + kg * 8;
#pragma unroll
      for (int i = 0; i < 4; ++i) {
        int row = wr * 64 + i * 16 + cl;
        a[i] = *(const half8*)(Al + row * 256 + (((k0 >> 3) ^ (row & 7)) << 3));
      }
#pragma unroll
      for (int j = 0; j < 4; ++j) {
        int n = wc * 64 + j * 16 + cl;
        b[j] = *(const half8*)(Bc + n * 64 + (((kl >> 3) ^ (n & 7)) << 3));
      }
#pragma unroll
      for (int i = 0; i < 4; ++i)
#pragma unroll
        for (int j = 0; j < 4; ++j)
          acc[i][j] = __builtin_amdgcn_mfma_f32_16x16x32_f16(a[i], b[j], acc[i][j], 0, 0, 0);
    }
    __syncthreads();
  }
  int b = bc1 >> 1, c0 = (bc1 & 1) * 256;
#pragma unroll
  for (int i = 0; i < 4; ++i)
#pragma unroll
    for (int q = 0; q < 4; ++q) {
      int p = p0 + wr * 64 + i * 16 + kg * 4 + q;
      float bov = bo[p];
#pragma unroll
      for (int j = 0; j < 4; ++j) {
        int col = wc * 64 + j * 16 + cl;
        out[(size_t)b * 131072 + (size_t)p * 512 + c0 + col] = acc[i][j][q] + bov;
      }
    }
}

// ---------------- finalize loss (reduces all partials, no atomics anywhere) ----------------
__global__ __launch_bounds__(256) void k_final(
    const float* __restrict__ bq, const float* __restrict__ bk,
    const float* __restrict__ bv, const float* __restrict__ bo,
    const float* __restrict__ pbw, const float* __restrict__ pbk,
    const float* __restrict__ pbv, float* __restrict__ loss_out) {
  __shared__ float r[4][5];
  float swq = pbw[threadIdx.x];
  float sbk = 0.f, sbv = 0.f;
  for (int i = threadIdx.x; i < 4096; i += 256) {
    sbk += pbk[i];
    sbv += pbv[i];
  }
  for (int i = threadIdx.x; i < 16384; i += 256) {
    sbk += fabsf(bk[i]);
    sbv += fabsf(bv[i]);
  }
  float a = bq[threadIdx.x];
  float sbq = a * a;
  float b = bo[threadIdx.x];
  float sbo = b * b;
  int lane = threadIdx.x & 63, w = threadIdx.x >> 6;
#pragma unroll
  for (int d = 1; d < 64; d <<= 1) {
    swq += __shfl_xor(swq, d);
    sbk += __shfl_xor(sbk, d);
    sbv += __shfl_xor(sbv, d);
    sbq += __shfl_xor(sbq, d);
    sbo += __shfl_xor(sbo, d);
  }
  if (lane == 0) {
    r[w][0] = swq; r[w][1] = sbk; r[w][2] = sbv; r[w][3] = sbq; r[w][4] = sbo;
  }
  __syncthreads();
  if (threadIdx.x == 0) {
    float twq = r[0][0] + r[1][0] + r[2][0] + r[3][0];
    float tbk = r[0][1] + r[1][1] + r[2][1] + r[3][1];
    float tbv = r[0][2] + r[1][2] + r[2][2] + r[3][2];
    float tbq = r[0][3] + r[1][3] + r[2][3] + r[3][3];
    float tbo = r[0][4] + r[1][4] + r[2][4] + r[3][4];
    float loss = 0.01f * (sqrtf(twq) + sqrtf(tbq) + sqrtf(tbo)) +
                 0.001f * (tbk + tbv);
    *loss_out = loss;
  }
}

extern "C" void kernel_launch(void* const* d_in, const int* in_sizes, int n_in,
                              void* d_out, int out_size, void* d_ws, size_t ws_size,
                              hipStream_t stream) {
  const float* in    = (const float*)d_in[0];
  const float* Wq    = (const float*)d_in[1];
  const float* bq    = (const float*)d_in[2];
  const float* Wk    = (const float*)d_in[3];
  const float* bk    = (const float*)d_in[4];
  const float* Wv    = (const float*)d_in[5];
  const float* bv    = (const float*)d_in[6];
  const float* Wo    = (const float*)d_in[7];
  const float* bo    = (const float*)d_in[8];
  const float* sigma = (const float*)d_in[9];
  float* out = (float*)d_out;

  char* ws = (char*)d_ws;
  unsigned short* xh     = (unsigned short*)(ws);               // 2MB
  unsigned short* woh    = (unsigned short*)(ws + 2097152);     // 128KB
  float*          bdiff  = (float*)(ws + 2228224);              // 64KB
  float*          rsig   = (float*)(ws + 2293760);              // 64KB
  float*          fire_s = (float*)(ws + 2359296);              // 1MB
  float*          nfs    = (float*)(ws + 3407872);              // 1MB
  unsigned short* ph     = (unsigned short*)(ws + 4456448);     // 2MB
  float*          pbk    = (float*)(ws + 6553600);              // 16KB [4096]
  float*          pbv    = (float*)(ws + 6569984);              // 16KB [4096]
  float*          pbw    = (float*)(ws + 6586368);              // 1KB  [256]
  unsigned short* wdh    = (unsigned short*)(ws + 6815744);     // 8MB (dead after k_fire)
  unsigned short* pp     = (unsigned short*)(ws + 6815744);     // 8MB partials (reuse)
  unsigned short* wvh    = (unsigned short*)(ws + 15204352);    // 8MB

  k_prep_x<<<dim3(16, 8, 8), 256, 0, stream>>>(in, xh);
  k_prep_w<<<4096, 256, 0, stream>>>(Wq, Wk, Wv, Wo, bq, bk, sigma,
                                     wdh, wvh, woh, bdiff, rsig, pbk, pbv);
  k_wqwo<<<256, 256, 0, stream>>>(Wq, Wo, pbw);
  k_fire<<<dim3(8, 32), 512, 0, stream>>>(xh, wdh, bdiff, rsig, fire_s);
  const float tau = (float)(0.9 * pow(1.0 / (64.0 + (double)EPS_F), 1.0 / 256.0));
  k_mask<<<1024, 256, 0, stream>>>(fire_s, nfs, tau);
  k_pred<<<dim3(4, 64), 512, 0, stream>>>(xh, wvh, bv, nfs, pp);
  k_p2h<<<512, 256, 0, stream>>>(pp, ph);
  k_out<<<dim3(2, 16), 512, 0, stream>>>(ph, woh, bo, out);
  k_final<<<1, 256, 0, stream>>>(bq, bk, bv, bo, pbw, pbk, pbv, out + 1048576);
}